// Round 9
// baseline (187.482 us; speedup 1.0000x reference)
//
#include <hip/hip_runtime.h>
#include <hip/hip_bf16.h>

typedef __bf16 bf16x8 __attribute__((ext_vector_type(8)));
typedef float f32x4 __attribute__((ext_vector_type(4)));

#define DEVI __device__ __forceinline__

constexpr int B_ = 2, T_ = 2048, C_ = 1024, H_ = 16, D_ = 64;
constexpr int M_ = B_ * T_;      // 4096 rows
constexpr int K_ = C_;           // 1024 inner dim (both GEMMs)
constexpr int WINDOW_ = 512;

DEVI unsigned short f2bf(float f) {
  return __builtin_bit_cast(unsigned short, (__bf16)f);  // RNE, 1 VALU op
}

DEVI void gl_lds16(const unsigned short* g, unsigned short* l) {
  __builtin_amdgcn_global_load_lds(
      (const __attribute__((address_space(1))) unsigned int*)g,
      (__attribute__((address_space(3))) unsigned int*)l, 16, 0, 0);
}

// ---------------- fused fp32 -> bf16 conversion (x, W_qkv, W_proj) ----------
__global__ void cvt_all(const float* __restrict__ x, const float* __restrict__ wqkv,
                        const float* __restrict__ wproj,
                        unsigned short* __restrict__ xb,
                        unsigned short* __restrict__ wqkvb,
                        unsigned short* __restrict__ wprojb) {
  constexpr int N1 = M_ * K_ / 4, N2 = 3 * C_ * K_ / 4, N3 = C_ * K_ / 4;
  int i = blockIdx.x * blockDim.x + threadIdx.x;
  const float* in;
  unsigned short* out;
  int idx;
  if (i < N1) { in = x; out = xb; idx = i; }
  else if (i < N1 + N2) { in = wqkv; out = wqkvb; idx = i - N1; }
  else if (i < N1 + N2 + N3) { in = wproj; out = wprojb; idx = i - N1 - N2; }
  else return;
  float4 v = reinterpret_cast<const float4*>(in)[idx];
  ushort4 o;
  o.x = f2bf(v.x); o.y = f2bf(v.y); o.z = f2bf(v.z); o.w = f2bf(v.w);
  reinterpret_cast<ushort4*>(out)[idx] = o;
}

// ---------------- bf16 GEMM: acc[m,n] = sum_k A[m,k]*W[n,k] ----------------
// 128^2 tile, BK=64, single-buffered gl_lds staging (round-7 skeleton).
// BK=64 halves barrier/drain count: 32 MFMA per barrier pair.
// Swizzle (mandatory at 128B rows): LDS slot (row,c16) holds global col
// c16^(row&7), achieved by pre-swizzling the per-lane GLOBAL source col
// (gl_lds dest stays linear); ds_read XORs the same -> 2-way (free).
// WHICH==0: A=x, W=W_qkv (N=3072) -> q,k,v each [B,H,T,64] bf16
// WHICH==1: A=att, W=W_proj (N=1024) -> fp32 out [M, C]
template <int WHICH>
__global__ __launch_bounds__(256) void gemm_bt(
    const unsigned short* __restrict__ A, const unsigned short* __restrict__ W,
    const float* __restrict__ bias,
    unsigned short* __restrict__ oq, unsigned short* __restrict__ ok,
    unsigned short* __restrict__ ov, float* __restrict__ of) {
  __shared__ alignas(16) unsigned short As[128 * 64];
  __shared__ alignas(16) unsigned short Bs[128 * 64];

  const int tid = threadIdx.x;
  const int n0 = blockIdx.x * 128, m0 = blockIdx.y * 128;
  const int lane = tid & 63, w = tid >> 6;
  const int wm = (w >> 1) * 64, wn = (w & 1) * 64;
  const int lr = lane & 15, lg = lane >> 4;

  // staging: lane -> row-in-8 (lane>>3), col16 (lane&7); global col pre-swizzled
  const int srow = lane >> 3;
  const int scol = ((lane & 7) ^ srow) << 3;   // elems; row&7 == lane>>3

  f32x4 acc[4][4];
#pragma unroll
  for (int i = 0; i < 4; i++)
#pragma unroll
    for (int j = 0; j < 4; j++) acc[i][j] = f32x4{0.f, 0.f, 0.f, 0.f};

  for (int kt = 0; kt < K_; kt += 64) {
#pragma unroll
    for (int i = 0; i < 4; i++) {
      const int rb = i * 32 + w * 8;           // wave-uniform base row
      gl_lds16(&A[(size_t)(m0 + rb + srow) * K_ + kt + scol], &As[rb * 64]);
    }
#pragma unroll
    for (int i = 0; i < 4; i++) {
      const int rb = i * 32 + w * 8;
      gl_lds16(&W[(size_t)(n0 + rb + srow) * K_ + kt + scol], &Bs[rb * 64]);
    }
    __syncthreads();

    bf16x8 af[4][2], bfr[4][2];
#pragma unroll
    for (int m = 0; m < 4; m++) {
      const int row = wm + m * 16 + lr;
      const int s = row & 7;
      af[m][0] = *reinterpret_cast<const bf16x8*>(&As[row * 64 + ((lg ^ s) << 3)]);
      af[m][1] = *reinterpret_cast<const bf16x8*>(&As[row * 64 + (((lg + 4) ^ s) << 3)]);
    }
#pragma unroll
    for (int n = 0; n < 4; n++) {
      const int row = wn + n * 16 + lr;
      const int s = row & 7;
      bfr[n][0] = *reinterpret_cast<const bf16x8*>(&Bs[row * 64 + ((lg ^ s) << 3)]);
      bfr[n][1] = *reinterpret_cast<const bf16x8*>(&Bs[row * 64 + (((lg + 4) ^ s) << 3)]);
    }
#pragma unroll
    for (int ks = 0; ks < 2; ks++)
#pragma unroll
      for (int m = 0; m < 4; m++)
#pragma unroll
        for (int n = 0; n < 4; n++)
          acc[m][n] = __builtin_amdgcn_mfma_f32_16x16x32_bf16(af[m][ks], bfr[n][ks], acc[m][n], 0, 0, 0);
    __syncthreads();
  }

#pragma unroll
  for (int ms = 0; ms < 4; ms++) {
#pragma unroll
    for (int ns = 0; ns < 4; ns++) {
#pragma unroll
      for (int r = 0; r < 4; r++) {
        int m = m0 + wm + ms * 16 + lg * 4 + r;
        int n = n0 + wn + ns * 16 + lr;
        if constexpr (WHICH == 0) {
          float v = acc[ms][ns][r] + bias[n];
          int part = n >> 10, nc = n & 1023;   // part lane-uniform per fragment
          int hh = nc >> 6, dd = nc & 63;
          int bb = m >> 11, tt = m & 2047;
          unsigned short bv = f2bf(v);
          size_t addr = (((size_t)(bb * H_ + hh)) * T_ + tt) * D_ + dd;
          if (part == 0) oq[addr] = bv;
          else if (part == 1) ok[addr] = bv;
          else ov[addr] = bv;
        } else {
          of[(size_t)m * C_ + n] = acc[ms][ns][r] + bias[n];
        }
      }
    }
  }
}

// ---------------- flash attention: window-causal + global prefix + softcap ---
// q,k,v: [B,H,T,64] bf16; out: [B*T, C] bf16
// 4 waves/block, 64-query tile, KVBLK=64 staged in XOR-swizzled LDS.
// V transposed during staging via pair-packed dword writes (2 kv per b32).
// Fixed-max softmax (scores softcapped to [-30,30] => M=30 always):
// p = exp(score-30) = exp2(C3 * rcp(1 + exp2(C1*s))), s = raw qk dot.
__global__ __launch_bounds__(256) void attn_fwd(
    const unsigned short* __restrict__ qg, const unsigned short* __restrict__ kg,
    const unsigned short* __restrict__ vg, const int* __restrict__ spl_arr,
    unsigned short* __restrict__ out) {
  const int tid = threadIdx.x;
  const int l = tid & 63, w = tid >> 6;
  const int lr = l & 15, lg = l >> 4;

  constexpr float C1 = 0.012022458674074695f;  // SCALE * log2(e) / 15
  constexpr float C3 = -86.56170245333781f;    // -60 * log2(e)

  // XCD swizzle: all 32 q-tiles of one (b,h) share lin%8 => same XCD.
  const int lin = blockIdx.x;             // 0..1023
  const int xs = lin & 7, slot = lin >> 3;
  const int g = xs + 8 * (slot >> 5);     // bh group 0..31
  const int iblk = slot & 31;             // q tile 0..31
  const int b = g >> 4, h = g & 15;
  const int q_base = iblk * 64;
  const int i0 = q_base + w * 16;         // this wave's 16 query rows

  const int spl = spl_arr[b];
  const size_t bh = (size_t)(b * H_ + h);
  const unsigned short* qp = qg + bh * T_ * D_;
  const unsigned short* kp = kg + bh * T_ * D_;
  const unsigned short* vp = vg + bh * T_ * D_;

  __shared__ alignas(16) unsigned short Ks[64 * 64];      // [kv][d], swizzled
  __shared__ alignas(16) unsigned short Vs[64 * 64];      // [d][kv], swizzled
  __shared__ alignas(16) unsigned short Ps[4][16][80];    // per-wave P, stride 80

  bf16x8 aq0 = *reinterpret_cast<const bf16x8*>(qp + (size_t)(i0 + lr) * D_ + lg * 8);
  bf16x8 aq1 = *reinterpret_cast<const bf16x8*>(qp + (size_t)(i0 + lr) * D_ + 32 + lg * 8);

  const unsigned short one_bf = 0x3F80;
  bf16x8 ONES;
#pragma unroll
  for (int i = 0; i < 8; i++) ONES[i] = __builtin_bit_cast(__bf16, one_bf);

  f32x4 acc[4];
  f32x4 accl = f32x4{0.f, 0.f, 0.f, 0.f};
#pragma unroll
  for (int nb = 0; nb < 4; nb++) acc[nb] = f32x4{0.f, 0.f, 0.f, 0.f};

  // tile schedule (block-level, union over 4 waves)
  const int pref_tiles = (spl + 63) >> 6;
  const int pref_end = pref_tiles << 6;
  int wl = q_base - WINDOW_; if (wl < 0) wl = 0; wl &= ~63;
  const int start2 = wl > pref_end ? wl : pref_end;
  const int hi = q_base + 63;
  const int n2 = (start2 <= hi) ? (((hi - start2) >> 6) + 1) : 0;
  const int ntot = pref_tiles + n2;

  // K staging: 4 lanes per kv row, 32B each
  const int strow = tid >> 2;              // 0..63 (kv row)
  const int c0 = (tid & 3) << 4;           // col segment base: 0,16,32,48 elems
  const int ssw = (strow & 7) << 3;        // XOR swizzle (8-elem units)
  // V staging: kv-pair p (rows 2p,2p+1), d-chunk c (8 cols)
  const int vpr = tid & 31, vc = tid >> 5;

  for (int tb = 0; tb < ntot; tb++) {
    const int j0 = (tb < pref_tiles) ? (tb << 6) : (start2 + ((tb - pref_tiles) << 6));
    {
      // K: direct copy [kv][d] with row-XOR swizzle
      const unsigned short* krow = kp + (size_t)(j0 + strow) * D_;
      int4 ka0 = *reinterpret_cast<const int4*>(krow + c0);
      int4 ka1 = *reinterpret_cast<const int4*>(krow + c0 + 8);
      *reinterpret_cast<int4*>(&Ks[strow * 64 + (c0 ^ ssw)]) = ka0;
      *reinterpret_cast<int4*>(&Ks[strow * 64 + ((c0 + 8) ^ ssw)]) = ka1;
      // V: transpose, pair-packed. Lane owns rows (2vpr, 2vpr+1), d = vc*8+e.
      union { int4 q4; unsigned short u[8]; } r0, r1;
      r0.q4 = *reinterpret_cast<const int4*>(vp + (size_t)(j0 + 2 * vpr) * D_ + vc * 8);
      r1.q4 = *reinterpret_cast<const int4*>(vp + (size_t)(j0 + 2 * vpr + 1) * D_ + vc * 8);
#pragma unroll
      for (int e = 0; e < 8; e++) {
        const int d = vc * 8 + e;
        unsigned pk = (unsigned)r0.u[e] | ((unsigned)r1.u[e] << 16);
        *reinterpret_cast<unsigned*>(&Vs[d * 64 + ((2 * vpr) ^ ((d & 7) << 3))]) = pk;
      }
    }
    __syncthreads();

    const bool rel = (j0 < spl) || (j0 + 63 >= i0 - WINDOW_ && j0 <= i0 + 15);
    if (rel) {
      // QK^T: S[16 q][64 kv] as 4 sub-tiles
      f32x4 s[4];
#pragma unroll
      for (int ks = 0; ks < 4; ks++) {
        const int krow = ks * 16 + lr;
        const int sw = (krow & 7) << 3;
        bf16x8 b0 = *reinterpret_cast<const bf16x8*>(&Ks[krow * 64 + ((lg * 8) ^ sw)]);
        bf16x8 b1 = *reinterpret_cast<const bf16x8*>(&Ks[krow * 64 + ((32 + lg * 8) ^ sw)]);
        f32x4 t = f32x4{0.f, 0.f, 0.f, 0.f};
        t = __builtin_amdgcn_mfma_f32_16x16x32_bf16(aq0, b0, t, 0, 0, 0);
        s[ks] = __builtin_amdgcn_mfma_f32_16x16x32_bf16(aq1, b1, t, 0, 0, 0);
      }

      // fused softcap+softmax with fixed max M=30
      const bool fullv = (j0 + 63 < spl) ||
                         ((j0 + 63 <= i0) && (i0 + 15 - j0 <= WINDOW_));
      if (fullv) {
#pragma unroll
        for (int r = 0; r < 4; r++) {
          const int prow = lg * 4 + r;
#pragma unroll
          for (int ks = 0; ks < 4; ks++) {
            float t = __builtin_amdgcn_exp2f(s[ks][r] * C1);
            float p = __builtin_amdgcn_exp2f(C3 * __builtin_amdgcn_rcpf(1.0f + t));
            Ps[w][prow][ks * 16 + lr] = f2bf(p);
          }
        }
      } else {
#pragma unroll
        for (int r = 0; r < 4; r++) {
          const int prow = lg * 4 + r;
          const int irow = i0 + prow;
#pragma unroll
          for (int ks = 0; ks < 4; ks++) {
            const int jc = j0 + ks * 16 + lr;
            float t = __builtin_amdgcn_exp2f(s[ks][r] * C1);
            float p = __builtin_amdgcn_exp2f(C3 * __builtin_amdgcn_rcpf(1.0f + t));
            bool valid = (jc <= irow && irow - jc <= WINDOW_) || (jc < spl);
            p = valid ? p : 0.0f;
            Ps[w][prow][ks * 16 + lr] = f2bf(p);
          }
        }
      }

      // ensure this wave's cross-lane P writes have landed in LDS
      asm volatile("s_waitcnt lgkmcnt(0)" ::: "memory");

      bf16x8 pa0 = *reinterpret_cast<const bf16x8*>(&Ps[w][lr][lg * 8]);
      bf16x8 pa1 = *reinterpret_cast<const bf16x8*>(&Ps[w][lr][32 + lg * 8]);

      // row sums via ones-MFMA (accumulates across tiles; no rescale needed)
      accl = __builtin_amdgcn_mfma_f32_16x16x32_bf16(pa0, ONES, accl, 0, 0, 0);
      accl = __builtin_amdgcn_mfma_f32_16x16x32_bf16(pa1, ONES, accl, 0, 0, 0);

#pragma unroll
      for (int nb = 0; nb < 4; nb++) {
        const int vrow = nb * 16 + lr;
        const int sw = (vrow & 7) << 3;
        bf16x8 bv0 = *reinterpret_cast<const bf16x8*>(&Vs[vrow * 64 + ((lg * 8) ^ sw)]);
        bf16x8 bv1 = *reinterpret_cast<const bf16x8*>(&Vs[vrow * 64 + ((32 + lg * 8) ^ sw)]);
        acc[nb] = __builtin_amdgcn_mfma_f32_16x16x32_bf16(pa0, bv0, acc[nb], 0, 0, 0);
        acc[nb] = __builtin_amdgcn_mfma_f32_16x16x32_bf16(pa1, bv1, acc[nb], 0, 0, 0);
      }
    }
    __syncthreads();
  }

  float rl[4];
#pragma unroll
  for (int r = 0; r < 4; r++) rl[r] = __builtin_amdgcn_rcpf(accl[r]);
#pragma unroll
  for (int nb = 0; nb < 4; nb++) {
#pragma unroll
    for (int r = 0; r < 4; r++) {
      float o = acc[nb][r] * rl[r];
      int t = i0 + lg * 4 + r;
      out[((size_t)(b * T_ + t)) * C_ + h * D_ + nb * 16 + lr] = f2bf(o);
    }
  }
}

extern "C" void kernel_launch(void* const* d_in, const int* in_sizes, int n_in,
                              void* d_out, int out_size, void* d_ws, size_t ws_size,
                              hipStream_t stream) {
  const float* x = (const float*)d_in[0];
  const int* spl = (const int*)d_in[1];
  const float* Wqkv = (const float*)d_in[2];
  const float* bqkv = (const float*)d_in[3];
  const float* Wproj = (const float*)d_in[4];
  const float* bproj = (const float*)d_in[5];
  float* out = (float*)d_out;

  char* ws = (char*)d_ws;
  unsigned short* xb = (unsigned short*)ws;       ws += (size_t)M_ * K_ * 2;        // 8 MB
  unsigned short* wqkvb = (unsigned short*)ws;    ws += (size_t)3 * C_ * K_ * 2;    // 6 MB
  unsigned short* wprojb = (unsigned short*)ws;   ws += (size_t)C_ * K_ * 2;        // 2 MB
  unsigned short* qb = (unsigned short*)ws;       ws += (size_t)M_ * C_ * 2;        // 8 MB
  unsigned short* kb = (unsigned short*)ws;       ws += (size_t)M_ * C_ * 2;        // 8 MB
  unsigned short* vb = (unsigned short*)ws;       ws += (size_t)M_ * C_ * 2;        // 8 MB
  unsigned short* ab = (unsigned short*)ws;       ws += (size_t)M_ * C_ * 2;        // 8 MB

  {
    constexpr int NT = (M_ * K_ + 3 * C_ * K_ + C_ * K_) / 4;
    cvt_all<<<(NT + 255) / 256, 256, 0, stream>>>(x, Wqkv, Wproj, xb, wqkvb, wprojb);
  }

  // Merged QKV projection: N=3072 -> 24x32 = 768 blocks (3/CU)
  gemm_bt<0><<<dim3(3072 / 128, M_ / 128), 256, 0, stream>>>(
      xb, wqkvb, bqkv, qb, kb, vb, nullptr);

  attn_fwd<<<dim3(1024), 256, 0, stream>>>(qb, kb, vb, spl, ab);

  // Output projection: N=1024 -> 8x32 = 256 blocks
  gemm_bt<1><<<dim3(C_ / 128, M_ / 128), 256, 0, stream>>>(
      ab, wprojb, bproj, nullptr, nullptr, nullptr, out);
}

// Round 10
// 168.552 us; speedup vs baseline: 1.1123x; 1.1123x over previous
//
#include <hip/hip_runtime.h>
#include <hip/hip_bf16.h>

typedef __bf16 bf16x8 __attribute__((ext_vector_type(8)));
typedef float f32x4 __attribute__((ext_vector_type(4)));

#define DEVI __device__ __forceinline__

constexpr int B_ = 2, T_ = 2048, C_ = 1024, H_ = 16, D_ = 64;
constexpr int M_ = B_ * T_;      // 4096 rows
constexpr int K_ = C_;           // 1024 inner dim (both GEMMs)
constexpr int WINDOW_ = 512;

DEVI unsigned short f2bf(float f) {
  return __builtin_bit_cast(unsigned short, (__bf16)f);  // RNE, 1 VALU op
}

DEVI void gl_lds16(const unsigned short* g, unsigned short* l) {
  __builtin_amdgcn_global_load_lds(
      (const __attribute__((address_space(1))) unsigned int*)g,
      (__attribute__((address_space(3))) unsigned int*)l, 16, 0, 0);
}

// ---------------- fused fp32 -> bf16 conversion (x, W_qkv, W_proj) ----------
__global__ void cvt_all(const float* __restrict__ x, const float* __restrict__ wqkv,
                        const float* __restrict__ wproj,
                        unsigned short* __restrict__ xb,
                        unsigned short* __restrict__ wqkvb,
                        unsigned short* __restrict__ wprojb) {
  constexpr int N1 = M_ * K_ / 4, N2 = 3 * C_ * K_ / 4, N3 = C_ * K_ / 4;
  int i = blockIdx.x * blockDim.x + threadIdx.x;
  const float* in;
  unsigned short* out;
  int idx;
  if (i < N1) { in = x; out = xb; idx = i; }
  else if (i < N1 + N2) { in = wqkv; out = wqkvb; idx = i - N1; }
  else if (i < N1 + N2 + N3) { in = wproj; out = wprojb; idx = i - N1 - N2; }
  else return;
  float4 v = reinterpret_cast<const float4*>(in)[idx];
  ushort4 o;
  o.x = f2bf(v.x); o.y = f2bf(v.y); o.z = f2bf(v.z); o.w = f2bf(v.w);
  reinterpret_cast<ushort4*>(out)[idx] = o;
}

// ---------------- bf16 GEMM: acc[m,n] = sum_k A[m,k]*W[n,k] ----------------
// BMxBN tile, BK=64, single-buffered gl_lds staging, 4 waves (2Mx2N).
// Small tiles -> high blocks/CU: round-9 PMC showed latency-bound (MfmaUtil
// 20%, Occ 15%) at 3 blocks/CU; this trades refetch (L2/L3-absorbed, HBM@17%)
// for wave-level overlap.
// Swizzle (0 conflicts, verified r9): LDS slot (row,c16) holds global col
// c16^(row&7) via pre-swizzled per-lane GLOBAL source (gl_lds dest linear);
// ds_read XORs the same -> 2-way (free).
// WHICH==0: A=x, W=W_qkv (N=3072) -> q,k,v each [B,H,T,64] bf16
// WHICH==1: A=att, W=W_proj (N=1024) -> fp32 out [M, C]
template <int WHICH, int BM, int BN>
__global__ __launch_bounds__(256) void gemm_bt(
    const unsigned short* __restrict__ A, const unsigned short* __restrict__ W,
    const float* __restrict__ bias,
    unsigned short* __restrict__ oq, unsigned short* __restrict__ ok,
    unsigned short* __restrict__ ov, float* __restrict__ of) {
  constexpr int NF = BN / 32;   // n-frags per wave
  __shared__ alignas(16) unsigned short As[BM * 64];
  __shared__ alignas(16) unsigned short Bs[BN * 64];

  const int tid = threadIdx.x;
  const int n0 = blockIdx.x * BN, m0 = blockIdx.y * BM;
  const int lane = tid & 63, w = tid >> 6;
  const int wm = (w >> 1) * 32, wn = (w & 1) * (BN / 2);
  const int lr = lane & 15, lg = lane >> 4;

  // staging: lane -> row-in-8 (lane>>3), col16 (lane&7); global col pre-swizzled
  const int srow = lane >> 3;
  const int scol = ((lane & 7) ^ srow) << 3;   // elems; row&7 == lane>>3

  f32x4 acc[2][NF];
#pragma unroll
  for (int i = 0; i < 2; i++)
#pragma unroll
    for (int j = 0; j < NF; j++) acc[i][j] = f32x4{0.f, 0.f, 0.f, 0.f};

  for (int kt = 0; kt < K_; kt += 64) {
#pragma unroll
    for (int i = 0; i < BM / 32; i++) {
      const int rb = w * (BM / 4) + i * 8;     // wave-uniform base row
      gl_lds16(&A[(size_t)(m0 + rb + srow) * K_ + kt + scol], &As[rb * 64]);
    }
#pragma unroll
    for (int i = 0; i < BN / 32; i++) {
      const int rb = w * (BN / 4) + i * 8;
      gl_lds16(&W[(size_t)(n0 + rb + srow) * K_ + kt + scol], &Bs[rb * 64]);
    }
    __syncthreads();

    bf16x8 af[2][2], bfr[NF][2];
#pragma unroll
    for (int m = 0; m < 2; m++) {
      const int row = wm + m * 16 + lr;
      const int s = row & 7;
      af[m][0] = *reinterpret_cast<const bf16x8*>(&As[row * 64 + ((lg ^ s) << 3)]);
      af[m][1] = *reinterpret_cast<const bf16x8*>(&As[row * 64 + (((lg + 4) ^ s) << 3)]);
    }
#pragma unroll
    for (int n = 0; n < NF; n++) {
      const int row = wn + n * 16 + lr;
      const int s = row & 7;
      bfr[n][0] = *reinterpret_cast<const bf16x8*>(&Bs[row * 64 + ((lg ^ s) << 3)]);
      bfr[n][1] = *reinterpret_cast<const bf16x8*>(&Bs[row * 64 + (((lg + 4) ^ s) << 3)]);
    }
#pragma unroll
    for (int ks = 0; ks < 2; ks++)
#pragma unroll
      for (int m = 0; m < 2; m++)
#pragma unroll
        for (int n = 0; n < NF; n++)
          acc[m][n] = __builtin_amdgcn_mfma_f32_16x16x32_bf16(af[m][ks], bfr[n][ks], acc[m][n], 0, 0, 0);
    __syncthreads();
  }

#pragma unroll
  for (int ms = 0; ms < 2; ms++) {
#pragma unroll
    for (int ns = 0; ns < NF; ns++) {
#pragma unroll
      for (int r = 0; r < 4; r++) {
        int m = m0 + wm + ms * 16 + lg * 4 + r;
        int n = n0 + wn + ns * 16 + lr;
        if constexpr (WHICH == 0) {
          float v = acc[ms][ns][r] + bias[n];
          int part = n >> 10, nc = n & 1023;   // part lane-uniform per fragment
          int hh = nc >> 6, dd = nc & 63;
          int bb = m >> 11, tt = m & 2047;
          unsigned short bv = f2bf(v);
          size_t addr = (((size_t)(bb * H_ + hh)) * T_ + tt) * D_ + dd;
          if (part == 0) oq[addr] = bv;
          else if (part == 1) ok[addr] = bv;
          else ov[addr] = bv;
        } else {
          of[(size_t)m * C_ + n] = acc[ms][ns][r] + bias[n];
        }
      }
    }
  }
}

// ---------------- flash attention: window-causal + global prefix + softcap ---
// q,k,v: [B,H,T,64] bf16; out: [B*T, C] bf16
// 4 waves/block, 64-query tile, KVBLK=64 staged in XOR-swizzled LDS.
// V transposed during staging via pair-packed dword writes (2 kv per b32).
// Fixed-max softmax (scores softcapped to [-30,30] => M=30 always):
// p = exp(score-30) = exp2(C3 * rcp(1 + exp2(C1*s))), s = raw qk dot.
__global__ __launch_bounds__(256) void attn_fwd(
    const unsigned short* __restrict__ qg, const unsigned short* __restrict__ kg,
    const unsigned short* __restrict__ vg, const int* __restrict__ spl_arr,
    unsigned short* __restrict__ out) {
  const int tid = threadIdx.x;
  const int l = tid & 63, w = tid >> 6;
  const int lr = l & 15, lg = l >> 4;

  constexpr float C1 = 0.012022458674074695f;  // SCALE * log2(e) / 15
  constexpr float C3 = -86.56170245333781f;    // -60 * log2(e)

  // XCD swizzle: all 32 q-tiles of one (b,h) share lin%8 => same XCD.
  const int lin = blockIdx.x;             // 0..1023
  const int xs = lin & 7, slot = lin >> 3;
  const int g = xs + 8 * (slot >> 5);     // bh group 0..31
  const int iblk = slot & 31;             // q tile 0..31
  const int b = g >> 4, h = g & 15;
  const int q_base = iblk * 64;
  const int i0 = q_base + w * 16;         // this wave's 16 query rows

  const int spl = spl_arr[b];
  const size_t bh = (size_t)(b * H_ + h);
  const unsigned short* qp = qg + bh * T_ * D_;
  const unsigned short* kp = kg + bh * T_ * D_;
  const unsigned short* vp = vg + bh * T_ * D_;

  __shared__ alignas(16) unsigned short Ks[64 * 64];      // [kv][d], swizzled
  __shared__ alignas(16) unsigned short Vs[64 * 64];      // [d][kv], swizzled
  __shared__ alignas(16) unsigned short Ps[4][16][80];    // per-wave P, stride 80

  bf16x8 aq0 = *reinterpret_cast<const bf16x8*>(qp + (size_t)(i0 + lr) * D_ + lg * 8);
  bf16x8 aq1 = *reinterpret_cast<const bf16x8*>(qp + (size_t)(i0 + lr) * D_ + 32 + lg * 8);

  const unsigned short one_bf = 0x3F80;
  bf16x8 ONES;
#pragma unroll
  for (int i = 0; i < 8; i++) ONES[i] = __builtin_bit_cast(__bf16, one_bf);

  f32x4 acc[4];
  f32x4 accl = f32x4{0.f, 0.f, 0.f, 0.f};
#pragma unroll
  for (int nb = 0; nb < 4; nb++) acc[nb] = f32x4{0.f, 0.f, 0.f, 0.f};

  // tile schedule (block-level, union over 4 waves)
  const int pref_tiles = (spl + 63) >> 6;
  const int pref_end = pref_tiles << 6;
  int wl = q_base - WINDOW_; if (wl < 0) wl = 0; wl &= ~63;
  const int start2 = wl > pref_end ? wl : pref_end;
  const int hi = q_base + 63;
  const int n2 = (start2 <= hi) ? (((hi - start2) >> 6) + 1) : 0;
  const int ntot = pref_tiles + n2;

  // K staging: 4 lanes per kv row, 32B each
  const int strow = tid >> 2;              // 0..63 (kv row)
  const int c0 = (tid & 3) << 4;           // col segment base: 0,16,32,48 elems
  const int ssw = (strow & 7) << 3;        // XOR swizzle (8-elem units)
  // V staging: kv-pair p (rows 2p,2p+1), d-chunk c (8 cols)
  const int vpr = tid & 31, vc = tid >> 5;

  for (int tb = 0; tb < ntot; tb++) {
    const int j0 = (tb < pref_tiles) ? (tb << 6) : (start2 + ((tb - pref_tiles) << 6));
    {
      // K: direct copy [kv][d] with row-XOR swizzle
      const unsigned short* krow = kp + (size_t)(j0 + strow) * D_;
      int4 ka0 = *reinterpret_cast<const int4*>(krow + c0);
      int4 ka1 = *reinterpret_cast<const int4*>(krow + c0 + 8);
      *reinterpret_cast<int4*>(&Ks[strow * 64 + (c0 ^ ssw)]) = ka0;
      *reinterpret_cast<int4*>(&Ks[strow * 64 + ((c0 + 8) ^ ssw)]) = ka1;
      // V: transpose, pair-packed. Lane owns rows (2vpr, 2vpr+1), d = vc*8+e.
      union { int4 q4; unsigned short u[8]; } r0, r1;
      r0.q4 = *reinterpret_cast<const int4*>(vp + (size_t)(j0 + 2 * vpr) * D_ + vc * 8);
      r1.q4 = *reinterpret_cast<const int4*>(vp + (size_t)(j0 + 2 * vpr + 1) * D_ + vc * 8);
#pragma unroll
      for (int e = 0; e < 8; e++) {
        const int d = vc * 8 + e;
        unsigned pk = (unsigned)r0.u[e] | ((unsigned)r1.u[e] << 16);
        *reinterpret_cast<unsigned*>(&Vs[d * 64 + ((2 * vpr) ^ ((d & 7) << 3))]) = pk;
      }
    }
    __syncthreads();

    const bool rel = (j0 < spl) || (j0 + 63 >= i0 - WINDOW_ && j0 <= i0 + 15);
    if (rel) {
      // QK^T: S[16 q][64 kv] as 4 sub-tiles
      f32x4 s[4];
#pragma unroll
      for (int ks = 0; ks < 4; ks++) {
        const int krow = ks * 16 + lr;
        const int sw = (krow & 7) << 3;
        bf16x8 b0 = *reinterpret_cast<const bf16x8*>(&Ks[krow * 64 + ((lg * 8) ^ sw)]);
        bf16x8 b1 = *reinterpret_cast<const bf16x8*>(&Ks[krow * 64 + ((32 + lg * 8) ^ sw)]);
        f32x4 t = f32x4{0.f, 0.f, 0.f, 0.f};
        t = __builtin_amdgcn_mfma_f32_16x16x32_bf16(aq0, b0, t, 0, 0, 0);
        s[ks] = __builtin_amdgcn_mfma_f32_16x16x32_bf16(aq1, b1, t, 0, 0, 0);
      }

      // fused softcap+softmax with fixed max M=30
      const bool fullv = (j0 + 63 < spl) ||
                         ((j0 + 63 <= i0) && (i0 + 15 - j0 <= WINDOW_));
      if (fullv) {
#pragma unroll
        for (int r = 0; r < 4; r++) {
          const int prow = lg * 4 + r;
#pragma unroll
          for (int ks = 0; ks < 4; ks++) {
            float t = __builtin_amdgcn_exp2f(s[ks][r] * C1);
            float p = __builtin_amdgcn_exp2f(C3 * __builtin_amdgcn_rcpf(1.0f + t));
            Ps[w][prow][ks * 16 + lr] = f2bf(p);
          }
        }
      } else {
#pragma unroll
        for (int r = 0; r < 4; r++) {
          const int prow = lg * 4 + r;
          const int irow = i0 + prow;
#pragma unroll
          for (int ks = 0; ks < 4; ks++) {
            const int jc = j0 + ks * 16 + lr;
            float t = __builtin_amdgcn_exp2f(s[ks][r] * C1);
            float p = __builtin_amdgcn_exp2f(C3 * __builtin_amdgcn_rcpf(1.0f + t));
            bool valid = (jc <= irow && irow - jc <= WINDOW_) || (jc < spl);
            p = valid ? p : 0.0f;
            Ps[w][prow][ks * 16 + lr] = f2bf(p);
          }
        }
      }

      // ensure this wave's cross-lane P writes have landed in LDS
      asm volatile("s_waitcnt lgkmcnt(0)" ::: "memory");

      bf16x8 pa0 = *reinterpret_cast<const bf16x8*>(&Ps[w][lr][lg * 8]);
      bf16x8 pa1 = *reinterpret_cast<const bf16x8*>(&Ps[w][lr][32 + lg * 8]);

      // row sums via ones-MFMA (accumulates across tiles; no rescale needed)
      accl = __builtin_amdgcn_mfma_f32_16x16x32_bf16(pa0, ONES, accl, 0, 0, 0);
      accl = __builtin_amdgcn_mfma_f32_16x16x32_bf16(pa1, ONES, accl, 0, 0, 0);

#pragma unroll
      for (int nb = 0; nb < 4; nb++) {
        const int vrow = nb * 16 + lr;
        const int sw = (vrow & 7) << 3;
        bf16x8 bv0 = *reinterpret_cast<const bf16x8*>(&Vs[vrow * 64 + ((lg * 8) ^ sw)]);
        bf16x8 bv1 = *reinterpret_cast<const bf16x8*>(&Vs[vrow * 64 + ((32 + lg * 8) ^ sw)]);
        acc[nb] = __builtin_amdgcn_mfma_f32_16x16x32_bf16(pa0, bv0, acc[nb], 0, 0, 0);
        acc[nb] = __builtin_amdgcn_mfma_f32_16x16x32_bf16(pa1, bv1, acc[nb], 0, 0, 0);
      }
    }
    __syncthreads();
  }

  float rl[4];
#pragma unroll
  for (int r = 0; r < 4; r++) rl[r] = __builtin_amdgcn_rcpf(accl[r]);
#pragma unroll
  for (int nb = 0; nb < 4; nb++) {
#pragma unroll
    for (int r = 0; r < 4; r++) {
      float o = acc[nb][r] * rl[r];
      int t = i0 + lg * 4 + r;
      out[((size_t)(b * T_ + t)) * C_ + h * D_ + nb * 16 + lr] = f2bf(o);
    }
  }
}

extern "C" void kernel_launch(void* const* d_in, const int* in_sizes, int n_in,
                              void* d_out, int out_size, void* d_ws, size_t ws_size,
                              hipStream_t stream) {
  const float* x = (const float*)d_in[0];
  const int* spl = (const int*)d_in[1];
  const float* Wqkv = (const float*)d_in[2];
  const float* bqkv = (const float*)d_in[3];
  const float* Wproj = (const float*)d_in[4];
  const float* bproj = (const float*)d_in[5];
  float* out = (float*)d_out;

  char* ws = (char*)d_ws;
  unsigned short* xb = (unsigned short*)ws;       ws += (size_t)M_ * K_ * 2;        // 8 MB
  unsigned short* wqkvb = (unsigned short*)ws;    ws += (size_t)3 * C_ * K_ * 2;    // 6 MB
  unsigned short* wprojb = (unsigned short*)ws;   ws += (size_t)C_ * K_ * 2;        // 2 MB
  unsigned short* qb = (unsigned short*)ws;       ws += (size_t)M_ * C_ * 2;        // 8 MB
  unsigned short* kb = (unsigned short*)ws;       ws += (size_t)M_ * C_ * 2;        // 8 MB
  unsigned short* vb = (unsigned short*)ws;       ws += (size_t)M_ * C_ * 2;        // 8 MB
  unsigned short* ab = (unsigned short*)ws;       ws += (size_t)M_ * C_ * 2;        // 8 MB

  {
    constexpr int NT = (M_ * K_ + 3 * C_ * K_ + C_ * K_) / 4;
    cvt_all<<<(NT + 255) / 256, 256, 0, stream>>>(x, Wqkv, Wproj, xb, wqkvb, wprojb);
  }

  // Merged QKV projection: 64x128 tiles -> 24x64 = 1536 blocks (6/CU)
  gemm_bt<0, 64, 128><<<dim3(3072 / 128, M_ / 64), 256, 0, stream>>>(
      xb, wqkvb, bqkv, qb, kb, vb, nullptr);

  attn_fwd<<<dim3(1024), 256, 0, stream>>>(qb, kb, vb, spl, ab);

  // Output projection: 64x64 tiles -> 16x64 = 1024 blocks (4/CU)
  gemm_bt<1, 64, 64><<<dim3(C_ / 64, M_ / 64), 256, 0, stream>>>(
      ab, wprojb, bproj, nullptr, nullptr, nullptr, out);
}